// Round 6
// baseline (227.237 us; speedup 1.0000x reference)
//
#include <hip/hip_runtime.h>
#include <math.h>

#define IFZ 256
#define KZ  16
#define AHZ 8
#define AFZ 32
#define HF  256   // AHZ*AFZ

typedef _Float16 half8 __attribute__((ext_vector_type(8)));
typedef _Float16 half4 __attribute__((ext_vector_type(4)));
typedef float    f32x4 __attribute__((ext_vector_type(4)));

// ---------------------------------------------------------------------------
// f32 -> f16 vector convert (x1 -> x1h)
// ---------------------------------------------------------------------------
__global__ void conv_f16(const float* __restrict__ in, _Float16* __restrict__ out, int n4)
{
    int i = blockIdx.x * 256 + threadIdx.x;
    if (i >= n4) return;
    float4 v = reinterpret_cast<const float4*>(in)[i];
    half4 h;
    h[0] = (_Float16)v.x; h[1] = (_Float16)v.y;
    h[2] = (_Float16)v.z; h[3] = (_Float16)v.w;
    reinterpret_cast<half4*>(out)[i] = h;
}

// ---------------------------------------------------------------------------
// Weight transpose + convert: WT[m][c][k] = (f16) W_m[k][c]   (5 x 256x256)
// m: 0=Wq 1=Wk 2=Wv 3=Wg 4=Wback
// ---------------------------------------------------------------------------
__global__ void conv_wt(const float* __restrict__ w0, const float* __restrict__ w1,
                        const float* __restrict__ w2, const float* __restrict__ w3,
                        const float* __restrict__ w4, _Float16* __restrict__ out)
{
    int k = blockIdx.x;      // 0..255
    int m = blockIdx.y;      // 0..4
    int c = threadIdx.x;     // 0..255
    const float* w = (m == 0) ? w0 : (m == 1) ? w1 : (m == 2) ? w2 : (m == 3) ? w3 : w4;
    out[(size_t)m * 65536 + (size_t)c * 256 + k] = (_Float16)w[(size_t)k * 256 + c];
}

// ---------------------------------------------------------------------------
// prep: c1T[c][f] (f16, [16][256]): cols 0-7 = g[f]*Wb[f][c], col 8 = 1, rest 0
//       c23[0..7] = sum_f g*Wb ; c23[8..15] = sum_f b*Wb
// ---------------------------------------------------------------------------
__global__ void prep_c1(const float* __restrict__ g, const float* __restrict__ b,
                        const float* __restrict__ Wb,
                        _Float16* __restrict__ c1T, float* __restrict__ c23)
{
    __shared__ float red[4][16];
    const int f = threadIdx.x;      // 0..255
    const int w = f >> 6, l = f & 63;
    const float gv = g[f], bv = b[f];
    float ph2[8], ph3[8];
    #pragma unroll
    for (int h = 0; h < 8; ++h) {
        float wv = Wb[(size_t)f * 8 + h];
        c1T[h * 256 + f] = (_Float16)(gv * wv);
        ph2[h] = gv * wv;
        ph3[h] = bv * wv;
    }
    c1T[8 * 256 + f] = (_Float16)1.0f;
    #pragma unroll
    for (int cc = 9; cc < 16; ++cc) c1T[cc * 256 + f] = (_Float16)0.0f;

    #pragma unroll
    for (int h = 0; h < 8; ++h) {
        #pragma unroll
        for (int o = 32; o > 0; o >>= 1) {
            ph2[h] += __shfl_xor(ph2[h], o);
            ph3[h] += __shfl_xor(ph3[h], o);
        }
        if (l == h) { red[w][h] = ph2[h]; red[w][8 + h] = ph3[h]; }
    }
    __syncthreads();
    if (f < 16) c23[f] = red[0][f] + red[1][f] + red[2][f] + red[3][f];
}

// ---------------------------------------------------------------------------
// Fused QKVG GEMM: one block computes a 64x64 tile of ALL FOUR projections.
// A staged once per k-step; 4 B-tiles; 16 MFMAs/k-step.
// Epilogues: m0->Q(rope), m1->K(rope), m2->V, m3->G(sigmoid+bg). All f16 out.
// ---------------------------------------------------------------------------
__launch_bounds__(256)
__global__ void gemm_qkvg(const _Float16* __restrict__ A, const _Float16* __restrict__ WT,
                          const float* __restrict__ pe, const float* __restrict__ bg,
                          _Float16* __restrict__ QH, _Float16* __restrict__ KH,
                          _Float16* __restrict__ VH, _Float16* __restrict__ GH, int N)
{
    __shared__ _Float16 as[64][40];
    __shared__ _Float16 bs[4][64][40];

    const int tid = threadIdx.x;
    const int l   = tid & 63;
    const int w   = tid >> 6;
    const int n0  = blockIdx.x * 64;
    const int c0  = blockIdx.y * 64;

    f32x4 acc[4][4];   // [matrix][col16-group]
    #pragma unroll
    for (int m = 0; m < 4; ++m)
        #pragma unroll
        for (int b = 0; b < 4; ++b)
            { acc[m][b][0]=0.f; acc[m][b][1]=0.f; acc[m][b][2]=0.f; acc[m][b][3]=0.f; }

    const int srow = tid >> 2;         // 0..63
    const int sch  = (tid & 3) * 8;    // 0,8,16,24

    for (int kt = 0; kt < 8; ++kt) {
        const int k0 = kt * 32;
        half8 av{};
        if (n0 + srow < N)
            av = *reinterpret_cast<const half8*>(A + (size_t)(n0 + srow) * IFZ + k0 + sch);
        half8 bv0 = *reinterpret_cast<const half8*>(WT + 0 * 65536 + (size_t)(c0 + srow) * IFZ + k0 + sch);
        half8 bv1 = *reinterpret_cast<const half8*>(WT + 1 * 65536 + (size_t)(c0 + srow) * IFZ + k0 + sch);
        half8 bv2 = *reinterpret_cast<const half8*>(WT + 2 * 65536 + (size_t)(c0 + srow) * IFZ + k0 + sch);
        half8 bv3 = *reinterpret_cast<const half8*>(WT + 3 * 65536 + (size_t)(c0 + srow) * IFZ + k0 + sch);
        __syncthreads();   // protect previous iteration's reads
        *reinterpret_cast<half8*>(&as[srow][sch])    = av;
        *reinterpret_cast<half8*>(&bs[0][srow][sch]) = bv0;
        *reinterpret_cast<half8*>(&bs[1][srow][sch]) = bv1;
        *reinterpret_cast<half8*>(&bs[2][srow][sch]) = bv2;
        *reinterpret_cast<half8*>(&bs[3][srow][sch]) = bv3;
        __syncthreads();

        half8 af = *reinterpret_cast<const half8*>(&as[16 * w + (l & 15)][8 * (l >> 4)]);
        #pragma unroll
        for (int m = 0; m < 4; ++m) {
            #pragma unroll
            for (int b = 0; b < 4; ++b) {
                half8 bf = *reinterpret_cast<const half8*>(&bs[m][16 * b + (l & 15)][8 * (l >> 4)]);
                acc[m][b] = __builtin_amdgcn_mfma_f32_16x16x32_f16(af, bf, acc[m][b], 0, 0, 0);
            }
        }
    }

    // C/D layout: col = c0 + 16b + (l&15), row = n0 + 16w + 4*(l>>4) + r
    #pragma unroll
    for (int r = 0; r < 4; ++r) {
        const int grow = n0 + 16 * w + ((l >> 4) << 2) + r;
        if (grow >= N) continue;
        float a0 = pe[(size_t)grow * AFZ + (l & 15)];
        float a1 = pe[(size_t)grow * AFZ + 16 + (l & 15)];
        float s0, c0f, s1, c1f;
        __sincosf(a0, &s0, &c0f);
        __sincosf(a1, &s1, &c1f);
        // Q, K with RoPE (pairs: col group pb holds f=l&15, pb+1 holds f=16+(l&15))
        #pragma unroll
        for (int m = 0; m < 2; ++m) {
            _Float16* o = m ? KH : QH;
            #pragma unroll
            for (int pb = 0; pb < 4; pb += 2) {
                float v0 = acc[m][pb][r], v1 = acc[m][pb + 1][r];
                o[(size_t)grow * HF + c0 + 16 * pb       + (l & 15)] = (_Float16)(v0 * c0f - v1 * s0);
                o[(size_t)grow * HF + c0 + 16 * (pb + 1) + (l & 15)] = (_Float16)(v1 * c1f + v0 * s1);
            }
        }
        // V plain
        #pragma unroll
        for (int b = 0; b < 4; ++b)
            VH[(size_t)grow * HF + c0 + 16 * b + (l & 15)] = (_Float16)acc[2][b][r];
        // G sigmoid(x@Wg + bg)
        #pragma unroll
        for (int b = 0; b < 4; ++b) {
            const int c = c0 + 16 * b + (l & 15);
            float v = acc[3][b][r] + bg[c];
            GH[(size_t)grow * HF + c] = (_Float16)(1.f / (1.f + __expf(-v)));
        }
    }
}

// ---------------------------------------------------------------------------
// bias2 via MFMA (unchanged): C1=[x]@[c1|1] -> P[h], S1; C2=[x^2]@same -> S2
// ---------------------------------------------------------------------------
__launch_bounds__(256)
__global__ void bias2_mfma(const float* __restrict__ x2,
                           const _Float16* __restrict__ c1T,
                           const float* __restrict__ c23,
                           float* __restrict__ out, int R)
{
    const int tid = threadIdx.x;
    const int l = tid & 63;
    const int w = tid >> 6;
    const int c = l & 15;      // col: head h for c<8, sum-col at c=8
    const int p = l >> 4;      // k-chunk (A) / row-quad (C)

    const int R0 = (blockIdx.x * 4 + w) * 16;
    if (R0 >= R) return;

    half8 bf[8];
    #pragma unroll
    for (int kt = 0; kt < 8; ++kt)
        bf[kt] = *reinterpret_cast<const half8*>(c1T + (size_t)c * 256 + kt * 32 + p * 8);

    const int arow = (R0 + c < R) ? (R0 + c) : (R - 1);   // A row = l&15
    const float* xr = x2 + (size_t)arow * IFZ + p * 8;

    f32x4 acc1 = {0.f, 0.f, 0.f, 0.f};
    f32x4 acc2 = {0.f, 0.f, 0.f, 0.f};
    #pragma unroll
    for (int kt = 0; kt < 8; ++kt) {
        float4 xa = *reinterpret_cast<const float4*>(xr + kt * 32);
        float4 xb = *reinterpret_cast<const float4*>(xr + kt * 32 + 4);
        half8 ax, ax2;
        ax[0] = (_Float16)xa.x; ax[1] = (_Float16)xa.y;
        ax[2] = (_Float16)xa.z; ax[3] = (_Float16)xa.w;
        ax[4] = (_Float16)xb.x; ax[5] = (_Float16)xb.y;
        ax[6] = (_Float16)xb.z; ax[7] = (_Float16)xb.w;
        ax2[0] = (_Float16)(xa.x * xa.x); ax2[1] = (_Float16)(xa.y * xa.y);
        ax2[2] = (_Float16)(xa.z * xa.z); ax2[3] = (_Float16)(xa.w * xa.w);
        ax2[4] = (_Float16)(xb.x * xb.x); ax2[5] = (_Float16)(xb.y * xb.y);
        ax2[6] = (_Float16)(xb.z * xb.z); ax2[7] = (_Float16)(xb.w * xb.w);
        acc1 = __builtin_amdgcn_mfma_f32_16x16x32_f16(ax,  bf[kt], acc1, 0, 0, 0);
        acc2 = __builtin_amdgcn_mfma_f32_16x16x32_f16(ax2, bf[kt], acc2, 0, 0, 0);
    }

    const float c2v = (c < 8) ? c23[c]     : 0.f;
    const float c3v = (c < 8) ? c23[8 + c] : 0.f;
    const int srcl = (l & 48) | 8;     // col-8 lane of this row-quad group
    #pragma unroll
    for (int j = 0; j < 4; ++j) {
        float s1 = __shfl(acc1[j], srcl);
        float s2 = __shfl(acc2[j], srcl);
        float m    = s1 * (1.f / 256.f);
        float var  = s2 * (1.f / 256.f) - m * m;
        float rstd = rsqrtf(var + 1e-5f);
        const int row = R0 + 4 * p + j;
        if (c < 8 && row < R)
            out[(size_t)row * 8 + c] = rstd * (acc1[j] - m * c2v) + c3v;
    }
}

// ---------------------------------------------------------------------------
// Attention: ONE WAVE PER NODE (4 nodes/block). No LDS, no __syncthreads.
// lane l holds elems 4l..4l+3 (head h = l>>3). Edge indices broadcast by shfl;
// scores reduced with 3 shfl_xor in 8-lane head groups; softmax in-register.
// ---------------------------------------------------------------------------
__launch_bounds__(256)
__global__ void attn_node(const _Float16* __restrict__ Qh, const _Float16* __restrict__ Kh,
                          const _Float16* __restrict__ Vh, const _Float16* __restrict__ Gh,
                          const int* __restrict__ eidx, const float* __restrict__ b2,
                          _Float16* __restrict__ AOh, int N)
{
    const int tid = threadIdx.x;
    const int l   = tid & 63;
    const int w   = tid >> 6;
    const int n   = blockIdx.x * 4 + w;
    if (n >= N) return;
    const int h = l >> 3;

    const int ei_reg = eidx[(size_t)n * KZ + (l & 15)];

    half4 qh4 = *reinterpret_cast<const half4*>(Qh + (size_t)n * HF + 4 * l);
    const float q0 = (float)qh4[0], q1 = (float)qh4[1],
                q2 = (float)qh4[2], q3 = (float)qh4[3];

    const float b2a = b2[(size_t)n * 128 + l];
    const float b2b = b2[(size_t)n * 128 + 64 + l];

    float sc[16];
    #pragma unroll
    for (int e = 0; e < 16; ++e) {
        const int row = __shfl(ei_reg, e);
        half4 kh4 = *reinterpret_cast<const half4*>(Kh + (size_t)row * HF + 4 * l);
        float s = q0 * (float)kh4[0] + q1 * (float)kh4[1]
                + q2 * (float)kh4[2] + q3 * (float)kh4[3];
        s += __shfl_xor(s, 1); s += __shfl_xor(s, 2); s += __shfl_xor(s, 4);
        sc[e] = s * 0.17677669529663687f;
    }
    #pragma unroll
    for (int e = 0; e < 8; ++e) sc[e]     += __shfl(b2a, e * 8 + h);
    #pragma unroll
    for (int e = 0; e < 8; ++e) sc[e + 8] += __shfl(b2b, e * 8 + h);

    float m = sc[0];
    #pragma unroll
    for (int e = 1; e < 16; ++e) m = fmaxf(m, sc[e]);
    float sum = 0.f;
    #pragma unroll
    for (int e = 0; e < 16; ++e) { sc[e] = __expf(sc[e] - m); sum += sc[e]; }
    const float inv = 1.f / sum;

    float o0 = 0.f, o1 = 0.f, o2 = 0.f, o3 = 0.f;
    #pragma unroll
    for (int e = 0; e < 16; ++e) {
        const int row = __shfl(ei_reg, e);
        half4 vh4 = *reinterpret_cast<const half4*>(Vh + (size_t)row * HF + 4 * l);
        const float we = sc[e] * inv;
        o0 = fmaf(we, (float)vh4[0], o0);
        o1 = fmaf(we, (float)vh4[1], o1);
        o2 = fmaf(we, (float)vh4[2], o2);
        o3 = fmaf(we, (float)vh4[3], o3);
    }

    half4 gh4 = *reinterpret_cast<const half4*>(Gh + (size_t)n * HF + 4 * l);
    half4 oh;
    oh[0] = (_Float16)(o0 * (float)gh4[0]);
    oh[1] = (_Float16)(o1 * (float)gh4[1]);
    oh[2] = (_Float16)(o2 * (float)gh4[2]);
    oh[3] = (_Float16)(o3 * (float)gh4[3]);
    *reinterpret_cast<half4*>(AOh + (size_t)n * HF + 4 * l) = oh;
}

// ---------------------------------------------------------------------------
// Fused back-GEMM + residual + final LN, writing d_out directly.
// Block = 64 rows; wave w owns rows 16w..16w+15 x ALL 256 cols (acc 16xf32x4).
// A (AO f16) staged once in LDS; B-frags streamed from L2-hot WT4.
// LN per row: 15 in-reg adds + 4 shfl_xor. No RAW buffer.
// ---------------------------------------------------------------------------
__launch_bounds__(256)
__global__ void gemm_back_ln(const _Float16* __restrict__ A, const _Float16* __restrict__ BT,
                             const float* __restrict__ bbk, const float* __restrict__ x1,
                             const float* __restrict__ g1, const float* __restrict__ b1,
                             float* __restrict__ out, int N)
{
    __shared__ _Float16 as[64][264];

    const int tid = threadIdx.x;
    const int l   = tid & 63;
    const int w   = tid >> 6;
    const int n0  = blockIdx.x * 64;

    // stage whole A-tile: 64 rows x 256 k
    {
        const int r     = tid >> 2;
        const int cbase = (tid & 3) * 64;
        #pragma unroll
        for (int i = 0; i < 8; ++i) {
            half8 v{};
            if (n0 + r < N)
                v = *reinterpret_cast<const half8*>(A + (size_t)(n0 + r) * IFZ + cbase + i * 8);
            *reinterpret_cast<half8*>(&as[r][cbase + i * 8]) = v;
        }
    }
    __syncthreads();

    f32x4 acc[16];
    #pragma unroll
    for (int bb = 0; bb < 16; ++bb)
        { acc[bb][0]=0.f; acc[bb][1]=0.f; acc[bb][2]=0.f; acc[bb][3]=0.f; }

    #pragma unroll 1
    for (int kt = 0; kt < 8; ++kt) {
        half8 af = *reinterpret_cast<const half8*>(&as[16 * w + (l & 15)][kt * 32 + 8 * (l >> 4)]);
        #pragma unroll
        for (int bb = 0; bb < 16; ++bb) {
            half8 bf = *reinterpret_cast<const half8*>(
                BT + (size_t)(16 * bb + (l & 15)) * IFZ + kt * 32 + 8 * (l >> 4));
            acc[bb] = __builtin_amdgcn_mfma_f32_16x16x32_f16(af, bf, acc[bb], 0, 0, 0);
        }
    }

    const int c15 = l & 15;
    const int p   = l >> 4;
    #pragma unroll
    for (int j = 0; j < 4; ++j) {
        const int grow = n0 + 16 * w + 4 * p + j;
        const bool ok  = grow < N;
        float v[16];
        float s = 0.f, qq = 0.f;
        #pragma unroll
        for (int bb = 0; bb < 16; ++bb) {
            const int c = 16 * bb + c15;
            float t = acc[bb][j] + bbk[c]
                    + 1.4142135623730951f * (ok ? x1[(size_t)grow * IFZ + c] : 0.f);
            v[bb] = t; s += t; qq += t * t;
        }
        s  += __shfl_xor(s, 1);  s  += __shfl_xor(s, 2);
        s  += __shfl_xor(s, 4);  s  += __shfl_xor(s, 8);
        qq += __shfl_xor(qq, 1); qq += __shfl_xor(qq, 2);
        qq += __shfl_xor(qq, 4); qq += __shfl_xor(qq, 8);
        const float m    = s * (1.f / 256.f);
        const float var  = qq * (1.f / 256.f) - m * m;
        const float rstd = rsqrtf(var + 1e-5f);
        if (ok) {
            #pragma unroll
            for (int bb = 0; bb < 16; ++bb) {
                const int c = 16 * bb + c15;
                out[(size_t)grow * IFZ + c] = (v[bb] - m) * rstd * g1[c] + b1[c];
            }
        }
    }
}

// ---------------------------------------------------------------------------
extern "C" void kernel_launch(void* const* d_in, const int* in_sizes, int n_in,
                              void* d_out, int out_size, void* d_ws, size_t ws_size,
                              hipStream_t stream)
{
    const float* x1   = (const float*)d_in[0];
    const float* x2   = (const float*)d_in[1];
    const float* pe   = (const float*)d_in[2];
    const int*   ei   = (const int*)d_in[3];
    const float* wq   = (const float*)d_in[4];
    const float* wk   = (const float*)d_in[5];
    const float* wv   = (const float*)d_in[6];
    const float* wb   = (const float*)d_in[7];
    const float* blng = (const float*)d_in[8];
    const float* blnb = (const float*)d_in[9];
    const float* wg   = (const float*)d_in[10];
    const float* bg   = (const float*)d_in[11];
    const float* wbk  = (const float*)d_in[12];
    const float* bbk  = (const float*)d_in[13];
    const float* g1   = (const float*)d_in[14];
    const float* b1   = (const float*)d_in[15];

    const int N = in_sizes[0] / IFZ;

    const size_t S2 = (((size_t)N * HF * 2) + 4095) & ~(size_t)4095;   // f16 buffer size
    char* base = (char*)d_ws;
    _Float16* X1H = (_Float16*)(base);
    _Float16* QH  = (_Float16*)(base + 1 * S2);
    _Float16* KH  = (_Float16*)(base + 2 * S2);
    _Float16* VH  = (_Float16*)(base + 3 * S2);
    _Float16* GH  = (_Float16*)(base + 4 * S2);
    float*    B2  = (float*)   (base + 5 * S2);                 // N*KZ*8 f32 == S2 bytes
    _Float16* WT  = (_Float16*)(base + 6 * S2);                 // 5 x 65536 f16 (640KB)
    _Float16* C1T = (_Float16*)(base + 6 * S2 + (1u << 20));    // 16x256 f16
    float*    C23 = (float*)   (base + 6 * S2 + (1u << 20) + 8192);
    _Float16* AOH = QH;   // reuse: wave n reads Q[n] then writes AO[n]

    conv_f16<<<dim3((N * IFZ / 4 + 255) / 256), 256, 0, stream>>>(x1, X1H, N * IFZ / 4);
    conv_wt<<<dim3(256, 5), 256, 0, stream>>>(wq, wk, wv, wg, wbk, WT);
    prep_c1<<<dim3(1), 256, 0, stream>>>(blng, blnb, wb, C1T, C23);

    const int nt = (N + 63) / 64;
    gemm_qkvg<<<dim3(nt, 4), 256, 0, stream>>>(X1H, WT, pe, bg, QH, KH, VH, GH, N);

    const int R = N * KZ;
    bias2_mfma<<<dim3((R + 63) / 64), 256, 0, stream>>>(x2, C1T, C23, B2, R);

    attn_node<<<dim3((N + 3) / 4), 256, 0, stream>>>(QH, KH, VH, GH, ei, B2, AOH, N);

    gemm_back_ln<<<dim3(nt), 256, 0, stream>>>(AOH, WT + 4 * 65536, bbk, x1, g1, b1,
                                               (float*)d_out, N);
}

// Round 8
// 188.744 us; speedup vs baseline: 1.2039x; 1.2039x over previous
//
#include <hip/hip_runtime.h>
#include <math.h>

#define IFZ 256
#define KZ  16
#define AHZ 8
#define AFZ 32
#define HF  256   // AHZ*AFZ

typedef _Float16 half8 __attribute__((ext_vector_type(8)));
typedef _Float16 half4 __attribute__((ext_vector_type(4)));
typedef float    f32x4 __attribute__((ext_vector_type(4)));

// ---------------------------------------------------------------------------
// f32 -> f16 vector convert (x1 -> x1h)
// ---------------------------------------------------------------------------
__global__ void conv_f16(const float* __restrict__ in, _Float16* __restrict__ out, int n4)
{
    int i = blockIdx.x * 256 + threadIdx.x;
    if (i >= n4) return;
    float4 v = reinterpret_cast<const float4*>(in)[i];
    half4 h;
    h[0] = (_Float16)v.x; h[1] = (_Float16)v.y;
    h[2] = (_Float16)v.z; h[3] = (_Float16)v.w;
    reinterpret_cast<half4*>(out)[i] = h;
}

// ---------------------------------------------------------------------------
// Weight transpose + convert: WT[m][c][k] = (f16) W_m[k][c]   (5 x 256x256)
// ---------------------------------------------------------------------------
__global__ void conv_wt(const float* __restrict__ w0, const float* __restrict__ w1,
                        const float* __restrict__ w2, const float* __restrict__ w3,
                        const float* __restrict__ w4, _Float16* __restrict__ out)
{
    int k = blockIdx.x;      // 0..255
    int m = blockIdx.y;      // 0..4
    int c = threadIdx.x;     // 0..255
    const float* w = (m == 0) ? w0 : (m == 1) ? w1 : (m == 2) ? w2 : (m == 3) ? w3 : w4;
    out[(size_t)m * 65536 + (size_t)c * 256 + k] = (_Float16)w[(size_t)k * 256 + c];
}

// ---------------------------------------------------------------------------
// prep: c1T[c][f] (f16, [16][256]): cols 0-7 = g[f]*Wb[f][c], col 8 = 1, rest 0
//       c23[0..7] = sum_f g*Wb ; c23[8..15] = sum_f b*Wb
// ---------------------------------------------------------------------------
__global__ void prep_c1(const float* __restrict__ g, const float* __restrict__ b,
                        const float* __restrict__ Wb,
                        _Float16* __restrict__ c1T, float* __restrict__ c23)
{
    __shared__ float red[4][16];
    const int f = threadIdx.x;      // 0..255
    const int w = f >> 6, l = f & 63;
    const float gv = g[f], bv = b[f];
    float ph2[8], ph3[8];
    #pragma unroll
    for (int h = 0; h < 8; ++h) {
        float wv = Wb[(size_t)f * 8 + h];
        c1T[h * 256 + f] = (_Float16)(gv * wv);
        ph2[h] = gv * wv;
        ph3[h] = bv * wv;
    }
    c1T[8 * 256 + f] = (_Float16)1.0f;
    #pragma unroll
    for (int cc = 9; cc < 16; ++cc) c1T[cc * 256 + f] = (_Float16)0.0f;

    #pragma unroll
    for (int h = 0; h < 8; ++h) {
        #pragma unroll
        for (int o = 32; o > 0; o >>= 1) {
            ph2[h] += __shfl_xor(ph2[h], o);
            ph3[h] += __shfl_xor(ph3[h], o);
        }
        if (l == h) { red[w][h] = ph2[h]; red[w][8 + h] = ph3[h]; }
    }
    __syncthreads();
    if (f < 16) c23[f] = red[0][f] + red[1][f] + red[2][f] + red[3][f];
}

// ---------------------------------------------------------------------------
// Fused QKVG GEMM with register-prefetch double buffering.
// ---------------------------------------------------------------------------
__launch_bounds__(256)
__global__ void gemm_qkvg(const _Float16* __restrict__ A, const _Float16* __restrict__ WT,
                          const float* __restrict__ pe, const float* __restrict__ bg,
                          _Float16* __restrict__ QH, _Float16* __restrict__ KH,
                          _Float16* __restrict__ VH, _Float16* __restrict__ GH, int N)
{
    __shared__ _Float16 as[64][40];
    __shared__ _Float16 bs[4][64][40];

    const int tid = threadIdx.x;
    const int l   = tid & 63;
    const int w   = tid >> 6;
    const int n0  = blockIdx.x * 64;
    const int c0  = blockIdx.y * 64;

    f32x4 acc[4][4];
    #pragma unroll
    for (int m = 0; m < 4; ++m)
        #pragma unroll
        for (int b = 0; b < 4; ++b)
            { acc[m][b][0]=0.f; acc[m][b][1]=0.f; acc[m][b][2]=0.f; acc[m][b][3]=0.f; }

    const int srow = tid >> 2;
    const int sch  = (tid & 3) * 8;
    const size_t aoff = (size_t)(n0 + srow) * IFZ + sch;
    const size_t boff = (size_t)(c0 + srow) * IFZ + sch;

    half8 av{}, bv0, bv1, bv2, bv3;
    if (n0 + srow < N) av = *reinterpret_cast<const half8*>(A + aoff);
    bv0 = *reinterpret_cast<const half8*>(WT + 0 * 65536 + boff);
    bv1 = *reinterpret_cast<const half8*>(WT + 1 * 65536 + boff);
    bv2 = *reinterpret_cast<const half8*>(WT + 2 * 65536 + boff);
    bv3 = *reinterpret_cast<const half8*>(WT + 3 * 65536 + boff);

    for (int kt = 0; kt < 8; ++kt) {
        __syncthreads();   // previous iteration's LDS reads done
        *reinterpret_cast<half8*>(&as[srow][sch])    = av;
        *reinterpret_cast<half8*>(&bs[0][srow][sch]) = bv0;
        *reinterpret_cast<half8*>(&bs[1][srow][sch]) = bv1;
        *reinterpret_cast<half8*>(&bs[2][srow][sch]) = bv2;
        *reinterpret_cast<half8*>(&bs[3][srow][sch]) = bv3;
        __syncthreads();

        half8 nav{}, nbv0{}, nbv1{}, nbv2{}, nbv3{};
        if (kt < 7) {
            const int k0 = (kt + 1) * 32;
            if (n0 + srow < N) nav = *reinterpret_cast<const half8*>(A + aoff + k0);
            nbv0 = *reinterpret_cast<const half8*>(WT + 0 * 65536 + boff + k0);
            nbv1 = *reinterpret_cast<const half8*>(WT + 1 * 65536 + boff + k0);
            nbv2 = *reinterpret_cast<const half8*>(WT + 2 * 65536 + boff + k0);
            nbv3 = *reinterpret_cast<const half8*>(WT + 3 * 65536 + boff + k0);
        }

        half8 af = *reinterpret_cast<const half8*>(&as[16 * w + (l & 15)][8 * (l >> 4)]);
        #pragma unroll
        for (int m = 0; m < 4; ++m) {
            #pragma unroll
            for (int b = 0; b < 4; ++b) {
                half8 bf = *reinterpret_cast<const half8*>(&bs[m][16 * b + (l & 15)][8 * (l >> 4)]);
                acc[m][b] = __builtin_amdgcn_mfma_f32_16x16x32_f16(af, bf, acc[m][b], 0, 0, 0);
            }
        }
        av = nav; bv0 = nbv0; bv1 = nbv1; bv2 = nbv2; bv3 = nbv3;
    }

    #pragma unroll
    for (int r = 0; r < 4; ++r) {
        const int grow = n0 + 16 * w + ((l >> 4) << 2) + r;
        if (grow >= N) continue;
        float a0 = pe[(size_t)grow * AFZ + (l & 15)];
        float a1 = pe[(size_t)grow * AFZ + 16 + (l & 15)];
        float s0, c0f, s1, c1f;
        __sincosf(a0, &s0, &c0f);
        __sincosf(a1, &s1, &c1f);
        #pragma unroll
        for (int m = 0; m < 2; ++m) {
            _Float16* o = m ? KH : QH;
            #pragma unroll
            for (int pb = 0; pb < 4; pb += 2) {
                float v0 = acc[m][pb][r], v1 = acc[m][pb + 1][r];
                o[(size_t)grow * HF + c0 + 16 * pb       + (l & 15)] = (_Float16)(v0 * c0f - v1 * s0);
                o[(size_t)grow * HF + c0 + 16 * (pb + 1) + (l & 15)] = (_Float16)(v1 * c1f + v0 * s1);
            }
        }
        #pragma unroll
        for (int b = 0; b < 4; ++b)
            VH[(size_t)grow * HF + c0 + 16 * b + (l & 15)] = (_Float16)acc[2][b][r];
        #pragma unroll
        for (int b = 0; b < 4; ++b) {
            const int c = c0 + 16 * b + (l & 15);
            float v = acc[3][b][r] + bg[c];
            GH[(size_t)grow * HF + c] = (_Float16)(1.f / (1.f + __expf(-v)));
        }
    }
}

// ---------------------------------------------------------------------------
// bias2 via MFMA, v2: ALL x2 loads hoisted (16 float4 in flight per lane,
// nontemporal via ext_vector f32x4 - x2 is single-use), then cvt+MFMA.
// ---------------------------------------------------------------------------
__launch_bounds__(256)
__global__ void bias2_mfma(const float* __restrict__ x2,
                           const _Float16* __restrict__ c1T,
                           const float* __restrict__ c23,
                           float* __restrict__ out, int R)
{
    const int tid = threadIdx.x;
    const int l = tid & 63;
    const int w = tid >> 6;
    const int c = l & 15;      // col: head h for c<8, sum-col at c=8
    const int p = l >> 4;      // k-chunk (A) / row-quad (C)

    const int R0 = (blockIdx.x * 4 + w) * 16;
    if (R0 >= R) return;

    const int arow = (R0 + c < R) ? (R0 + c) : (R - 1);
    const float* xr = x2 + (size_t)arow * IFZ + p * 8;

    f32x4 xv[16];
    #pragma unroll
    for (int kt = 0; kt < 8; ++kt) {
        xv[2 * kt]     = __builtin_nontemporal_load(reinterpret_cast<const f32x4*>(xr + kt * 32));
        xv[2 * kt + 1] = __builtin_nontemporal_load(reinterpret_cast<const f32x4*>(xr + kt * 32 + 4));
    }

    half8 bf[8];
    #pragma unroll
    for (int kt = 0; kt < 8; ++kt)
        bf[kt] = *reinterpret_cast<const half8*>(c1T + (size_t)c * 256 + kt * 32 + p * 8);

    f32x4 acc1 = {0.f, 0.f, 0.f, 0.f};
    f32x4 acc2 = {0.f, 0.f, 0.f, 0.f};
    #pragma unroll
    for (int kt = 0; kt < 8; ++kt) {
        f32x4 xa = xv[2 * kt], xb = xv[2 * kt + 1];
        half8 ax, ax2;
        ax[0] = (_Float16)xa[0]; ax[1] = (_Float16)xa[1];
        ax[2] = (_Float16)xa[2]; ax[3] = (_Float16)xa[3];
        ax[4] = (_Float16)xb[0]; ax[5] = (_Float16)xb[1];
        ax[6] = (_Float16)xb[2]; ax[7] = (_Float16)xb[3];
        ax2[0] = (_Float16)(xa[0] * xa[0]); ax2[1] = (_Float16)(xa[1] * xa[1]);
        ax2[2] = (_Float16)(xa[2] * xa[2]); ax2[3] = (_Float16)(xa[3] * xa[3]);
        ax2[4] = (_Float16)(xb[0] * xb[0]); ax2[5] = (_Float16)(xb[1] * xb[1]);
        ax2[6] = (_Float16)(xb[2] * xb[2]); ax2[7] = (_Float16)(xb[3] * xb[3]);
        acc1 = __builtin_amdgcn_mfma_f32_16x16x32_f16(ax,  bf[kt], acc1, 0, 0, 0);
        acc2 = __builtin_amdgcn_mfma_f32_16x16x32_f16(ax2, bf[kt], acc2, 0, 0, 0);
    }

    const float c2v = (c < 8) ? c23[c]     : 0.f;
    const float c3v = (c < 8) ? c23[8 + c] : 0.f;
    const int srcl = (l & 48) | 8;
    #pragma unroll
    for (int j = 0; j < 4; ++j) {
        float s1 = __shfl(acc1[j], srcl);
        float s2 = __shfl(acc2[j], srcl);
        float m    = s1 * (1.f / 256.f);
        float var  = s2 * (1.f / 256.f) - m * m;
        float rstd = rsqrtf(var + 1e-5f);
        const int row = R0 + 4 * p + j;
        if (c < 8 && row < R)
            out[(size_t)row * 8 + c] = rstd * (acc1[j] - m * c2v) + c3v;
    }
}

// ---------------------------------------------------------------------------
// Attention: ONE WAVE PER NODE (4 nodes/block). No LDS, no __syncthreads.
// ---------------------------------------------------------------------------
__launch_bounds__(256)
__global__ void attn_node(const _Float16* __restrict__ Qh, const _Float16* __restrict__ Kh,
                          const _Float16* __restrict__ Vh, const _Float16* __restrict__ Gh,
                          const int* __restrict__ eidx, const float* __restrict__ b2,
                          _Float16* __restrict__ AOh, int N)
{
    const int tid = threadIdx.x;
    const int l   = tid & 63;
    const int w   = tid >> 6;
    const int n   = blockIdx.x * 4 + w;
    if (n >= N) return;
    const int h = l >> 3;

    const int ei_reg = eidx[(size_t)n * KZ + (l & 15)];

    half4 qh4 = *reinterpret_cast<const half4*>(Qh + (size_t)n * HF + 4 * l);
    const float q0 = (float)qh4[0], q1 = (float)qh4[1],
                q2 = (float)qh4[2], q3 = (float)qh4[3];

    const float b2a = b2[(size_t)n * 128 + l];
    const float b2b = b2[(size_t)n * 128 + 64 + l];

    float sc[16];
    #pragma unroll
    for (int e = 0; e < 16; ++e) {
        const int row = __shfl(ei_reg, e);
        half4 kh4 = *reinterpret_cast<const half4*>(Kh + (size_t)row * HF + 4 * l);
        float s = q0 * (float)kh4[0] + q1 * (float)kh4[1]
                + q2 * (float)kh4[2] + q3 * (float)kh4[3];
        s += __shfl_xor(s, 1); s += __shfl_xor(s, 2); s += __shfl_xor(s, 4);
        sc[e] = s * 0.17677669529663687f;
    }
    #pragma unroll
    for (int e = 0; e < 8; ++e) sc[e]     += __shfl(b2a, e * 8 + h);
    #pragma unroll
    for (int e = 0; e < 8; ++e) sc[e + 8] += __shfl(b2b, e * 8 + h);

    float m = sc[0];
    #pragma unroll
    for (int e = 1; e < 16; ++e) m = fmaxf(m, sc[e]);
    float sum = 0.f;
    #pragma unroll
    for (int e = 0; e < 16; ++e) { sc[e] = __expf(sc[e] - m); sum += sc[e]; }
    const float inv = 1.f / sum;

    float o0 = 0.f, o1 = 0.f, o2 = 0.f, o3 = 0.f;
    #pragma unroll
    for (int e = 0; e < 16; ++e) {
        const int row = __shfl(ei_reg, e);
        half4 vh4 = *reinterpret_cast<const half4*>(Vh + (size_t)row * HF + 4 * l);
        const float we = sc[e] * inv;
        o0 = fmaf(we, (float)vh4[0], o0);
        o1 = fmaf(we, (float)vh4[1], o1);
        o2 = fmaf(we, (float)vh4[2], o2);
        o3 = fmaf(we, (float)vh4[3], o3);
    }

    half4 gh4 = *reinterpret_cast<const half4*>(Gh + (size_t)n * HF + 4 * l);
    half4 oh;
    oh[0] = (_Float16)(o0 * (float)gh4[0]);
    oh[1] = (_Float16)(o1 * (float)gh4[1]);
    oh[2] = (_Float16)(o2 * (float)gh4[2]);
    oh[3] = (_Float16)(o3 * (float)gh4[3]);
    *reinterpret_cast<half4*>(AOh + (size_t)n * HF + 4 * l) = oh;
}

// ---------------------------------------------------------------------------
// back-GEMM: LDS-staged 64x64 tiles + reg prefetch; Y = AO@Wback + bbk (f32)
// ---------------------------------------------------------------------------
__launch_bounds__(256)
__global__ void gemm_back(const _Float16* __restrict__ A, const _Float16* __restrict__ BT,
                          const float* __restrict__ bias, float* __restrict__ Y, int N)
{
    __shared__ _Float16 as[64][40];
    __shared__ _Float16 bs[64][40];

    const int tid = threadIdx.x;
    const int l   = tid & 63;
    const int w   = tid >> 6;
    const int n0  = blockIdx.x * 64;
    const int c0  = blockIdx.y * 64;

    f32x4 acc[4];
    #pragma unroll
    for (int b = 0; b < 4; ++b) { acc[b][0]=0.f; acc[b][1]=0.f; acc[b][2]=0.f; acc[b][3]=0.f; }

    const int srow = tid >> 2;
    const int sch  = (tid & 3) * 8;
    const size_t aoff = (size_t)(n0 + srow) * IFZ + sch;
    const size_t boff = (size_t)(c0 + srow) * IFZ + sch;

    half8 av{}, bv;
    if (n0 + srow < N) av = *reinterpret_cast<const half8*>(A + aoff);
    bv = *reinterpret_cast<const half8*>(BT + boff);

    for (int kt = 0; kt < 8; ++kt) {
        __syncthreads();
        *reinterpret_cast<half8*>(&as[srow][sch]) = av;
        *reinterpret_cast<half8*>(&bs[srow][sch]) = bv;
        __syncthreads();

        half8 nav{}, nbv{};
        if (kt < 7) {
            const int k0 = (kt + 1) * 32;
            if (n0 + srow < N) nav = *reinterpret_cast<const half8*>(A + aoff + k0);
            nbv = *reinterpret_cast<const half8*>(BT + boff + k0);
        }

        half8 af = *reinterpret_cast<const half8*>(&as[16 * w + (l & 15)][8 * (l >> 4)]);
        #pragma unroll
        for (int b = 0; b < 4; ++b) {
            half8 bf = *reinterpret_cast<const half8*>(&bs[16 * b + (l & 15)][8 * (l >> 4)]);
            acc[b] = __builtin_amdgcn_mfma_f32_16x16x32_f16(af, bf, acc[b], 0, 0, 0);
        }
        av = nav; bv = nbv;
    }

    #pragma unroll
    for (int r = 0; r < 4; ++r) {
        const int grow = n0 + 16 * w + ((l >> 4) << 2) + r;
        if (grow >= N) continue;
        #pragma unroll
        for (int b = 0; b < 4; ++b) {
            const int c = c0 + 16 * b + (l & 15);
            Y[(size_t)grow * HF + c] = acc[b][r] + bias[c];
        }
    }
}

// ---------------------------------------------------------------------------
// final: LN( RAW + sqrt(2)*x1 ) -> out     (one wave per row)
// ---------------------------------------------------------------------------
__launch_bounds__(256)
__global__ void final_ln(const float* __restrict__ RAWb,
                         const float* __restrict__ x1b,
                         const float* __restrict__ g1,
                         const float* __restrict__ b1,
                         float* __restrict__ outb,
                         int N)
{
    int n    = blockIdx.x * 4 + (threadIdx.x >> 6);
    int lane = threadIdx.x & 63;
    if (n >= N) return;
    const size_t off = (size_t)n * IFZ + lane * 4;
    float4 ur = *reinterpret_cast<const float4*>(RAWb + off);
    float4 ux = *reinterpret_cast<const float4*>(x1b + off);
    float x[4];
    x[0] = ur.x + 1.4142135623730951f * ux.x;
    x[1] = ur.y + 1.4142135623730951f * ux.y;
    x[2] = ur.z + 1.4142135623730951f * ux.z;
    x[3] = ur.w + 1.4142135623730951f * ux.w;
    float s = x[0] + x[1] + x[2] + x[3];
    float q = x[0]*x[0] + x[1]*x[1] + x[2]*x[2] + x[3]*x[3];
    #pragma unroll
    for (int o = 32; o > 0; o >>= 1) { s += __shfl_xor(s, o); q += __shfl_xor(q, o); }
    float m    = s * (1.f / 256.f);
    float var  = q * (1.f / 256.f) - m * m;
    float rstd = rsqrtf(var + 1e-5f);
    float4 uo;
    {
        int f = lane * 4;
        uo.x = (x[0] - m) * rstd * g1[f + 0] + b1[f + 0];
        uo.y = (x[1] - m) * rstd * g1[f + 1] + b1[f + 1];
        uo.z = (x[2] - m) * rstd * g1[f + 2] + b1[f + 2];
        uo.w = (x[3] - m) * rstd * g1[f + 3] + b1[f + 3];
    }
    *reinterpret_cast<float4*>(outb + off) = uo;
}

// ---------------------------------------------------------------------------
extern "C" void kernel_launch(void* const* d_in, const int* in_sizes, int n_in,
                              void* d_out, int out_size, void* d_ws, size_t ws_size,
                              hipStream_t stream)
{
    const float* x1   = (const float*)d_in[0];
    const float* x2   = (const float*)d_in[1];
    const float* pe   = (const float*)d_in[2];
    const int*   ei   = (const int*)d_in[3];
    const float* wq   = (const float*)d_in[4];
    const float* wk   = (const float*)d_in[5];
    const float* wv   = (const float*)d_in[6];
    const float* wb   = (const float*)d_in[7];
    const float* blng = (const float*)d_in[8];
    const float* blnb = (const float*)d_in[9];
    const float* wg   = (const float*)d_in[10];
    const float* bg   = (const float*)d_in[11];
    const float* wbk  = (const float*)d_in[12];
    const float* bbk  = (const float*)d_in[13];
    const float* g1   = (const float*)d_in[14];
    const float* b1   = (const float*)d_in[15];

    const int N = in_sizes[0] / IFZ;

    const size_t S2 = (((size_t)N * HF * 2) + 4095) & ~(size_t)4095;   // f16 buffer size
    char* base = (char*)d_ws;
    _Float16* X1H = (_Float16*)(base);
    _Float16* QH  = (_Float16*)(base + 1 * S2);
    _Float16* KH  = (_Float16*)(base + 2 * S2);
    _Float16* VH  = (_Float16*)(base + 3 * S2);
    _Float16* GH  = (_Float16*)(base + 4 * S2);
    float*    B2  = (float*)   (base + 5 * S2);                 // N*KZ*8 f32 == S2 bytes
    _Float16* WT  = (_Float16*)(base + 6 * S2);                 // 5 x 65536 f16 (640KB)
    _Float16* C1T = (_Float16*)(base + 6 * S2 + (1u << 20));    // 16x256 f16
    float*    C23 = (float*)   (base + 6 * S2 + (1u << 20) + 8192);
    _Float16* AOH = QH;                  // reuse: wave n reads Q[n] then writes AO[n]
    float*    RAW = (float*)(base + 2 * S2);   // reuse KH+VH region (f32, 2*S2 bytes)

    conv_f16<<<dim3((N * IFZ / 4 + 255) / 256), 256, 0, stream>>>(x1, X1H, N * IFZ / 4);
    conv_wt<<<dim3(256, 5), 256, 0, stream>>>(wq, wk, wv, wg, wbk, WT);
    prep_c1<<<dim3(1), 256, 0, stream>>>(blng, blnb, wb, C1T, C23);

    const int nt = (N + 63) / 64;
    gemm_qkvg<<<dim3(nt, 4), 256, 0, stream>>>(X1H, WT, pe, bg, QH, KH, VH, GH, N);

    const int R = N * KZ;
    bias2_mfma<<<dim3((R + 63) / 64), 256, 0, stream>>>(x2, C1T, C23, B2, R);

    attn_node<<<dim3((N + 3) / 4), 256, 0, stream>>>(QH, KH, VH, GH, ei, B2, AOH, N);

    gemm_back<<<dim3(nt, 4), 256, 0, stream>>>(AOH, WT + 4 * 65536, bbk, RAW, N);

    final_ln<<<dim3((N + 3) / 4), 256, 0, stream>>>(RAW, x1, g1, b1, (float*)d_out, N);
}

// Round 9
// 168.118 us; speedup vs baseline: 1.3516x; 1.1227x over previous
//
#include <hip/hip_runtime.h>
#include <math.h>

#define IFZ 256
#define KZ  16
#define AHZ 8
#define AFZ 32
#define HF  256   // AHZ*AFZ

typedef _Float16 half8 __attribute__((ext_vector_type(8)));
typedef _Float16 half4 __attribute__((ext_vector_type(4)));
typedef float    f32x4 __attribute__((ext_vector_type(4)));

// ---------------------------------------------------------------------------
// f32 -> f16 vector convert (x1 -> x1h)
// ---------------------------------------------------------------------------
__global__ void conv_f16(const float* __restrict__ in, _Float16* __restrict__ out, int n4)
{
    int i = blockIdx.x * 256 + threadIdx.x;
    if (i >= n4) return;
    float4 v = reinterpret_cast<const float4*>(in)[i];
    half4 h;
    h[0] = (_Float16)v.x; h[1] = (_Float16)v.y;
    h[2] = (_Float16)v.z; h[3] = (_Float16)v.w;
    reinterpret_cast<half4*>(out)[i] = h;
}

// ---------------------------------------------------------------------------
// prep_all: y<5 -> WT[m][c][k] = (f16) W_m[k][c];  y==5,x==0 -> c1T/c23 prep
// ---------------------------------------------------------------------------
__global__ void prep_all(const float* __restrict__ w0, const float* __restrict__ w1,
                         const float* __restrict__ w2, const float* __restrict__ w3,
                         const float* __restrict__ w4, _Float16* __restrict__ out,
                         const float* __restrict__ g, const float* __restrict__ b,
                         const float* __restrict__ Wb,
                         _Float16* __restrict__ c1T, float* __restrict__ c23)
{
    const int m = blockIdx.y;
    if (m < 5) {
        int k = blockIdx.x;      // 0..255
        int c = threadIdx.x;     // 0..255
        const float* w = (m == 0) ? w0 : (m == 1) ? w1 : (m == 2) ? w2 : (m == 3) ? w3 : w4;
        out[(size_t)m * 65536 + (size_t)c * 256 + k] = (_Float16)w[(size_t)k * 256 + c];
        return;
    }
    if (blockIdx.x != 0) return;

    __shared__ float red[4][16];
    const int f = threadIdx.x;      // 0..255
    const int w = f >> 6, l = f & 63;
    const float gv = g[f], bv = b[f];
    float ph2[8], ph3[8];
    #pragma unroll
    for (int h = 0; h < 8; ++h) {
        float wv = Wb[(size_t)f * 8 + h];
        c1T[h * 256 + f] = (_Float16)(gv * wv);
        ph2[h] = gv * wv;
        ph3[h] = bv * wv;
    }
    c1T[8 * 256 + f] = (_Float16)1.0f;
    #pragma unroll
    for (int cc = 9; cc < 16; ++cc) c1T[cc * 256 + f] = (_Float16)0.0f;

    #pragma unroll
    for (int h = 0; h < 8; ++h) {
        #pragma unroll
        for (int o = 32; o > 0; o >>= 1) {
            ph2[h] += __shfl_xor(ph2[h], o);
            ph3[h] += __shfl_xor(ph3[h], o);
        }
        if (l == h) { red[w][h] = ph2[h]; red[w][8 + h] = ph3[h]; }
    }
    __syncthreads();
    if (f < 16) c23[f] = red[0][f] + red[1][f] + red[2][f] + red[3][f];
}

// ---------------------------------------------------------------------------
// Fused QKVG GEMM with register-prefetch double buffering.
// ---------------------------------------------------------------------------
__launch_bounds__(256)
__global__ void gemm_qkvg(const _Float16* __restrict__ A, const _Float16* __restrict__ WT,
                          const float* __restrict__ pe, const float* __restrict__ bg,
                          _Float16* __restrict__ QH, _Float16* __restrict__ KH,
                          _Float16* __restrict__ VH, _Float16* __restrict__ GH, int N)
{
    __shared__ _Float16 as[64][40];
    __shared__ _Float16 bs[4][64][40];

    const int tid = threadIdx.x;
    const int l   = tid & 63;
    const int w   = tid >> 6;
    const int n0  = blockIdx.x * 64;
    const int c0  = blockIdx.y * 64;

    f32x4 acc[4][4];
    #pragma unroll
    for (int m = 0; m < 4; ++m)
        #pragma unroll
        for (int b = 0; b < 4; ++b)
            { acc[m][b][0]=0.f; acc[m][b][1]=0.f; acc[m][b][2]=0.f; acc[m][b][3]=0.f; }

    const int srow = tid >> 2;
    const int sch  = (tid & 3) * 8;
    const size_t aoff = (size_t)(n0 + srow) * IFZ + sch;
    const size_t boff = (size_t)(c0 + srow) * IFZ + sch;

    half8 av{}, bv0, bv1, bv2, bv3;
    if (n0 + srow < N) av = *reinterpret_cast<const half8*>(A + aoff);
    bv0 = *reinterpret_cast<const half8*>(WT + 0 * 65536 + boff);
    bv1 = *reinterpret_cast<const half8*>(WT + 1 * 65536 + boff);
    bv2 = *reinterpret_cast<const half8*>(WT + 2 * 65536 + boff);
    bv3 = *reinterpret_cast<const half8*>(WT + 3 * 65536 + boff);

    for (int kt = 0; kt < 8; ++kt) {
        __syncthreads();   // previous iteration's LDS reads done
        *reinterpret_cast<half8*>(&as[srow][sch])    = av;
        *reinterpret_cast<half8*>(&bs[0][srow][sch]) = bv0;
        *reinterpret_cast<half8*>(&bs[1][srow][sch]) = bv1;
        *reinterpret_cast<half8*>(&bs[2][srow][sch]) = bv2;
        *reinterpret_cast<half8*>(&bs[3][srow][sch]) = bv3;
        __syncthreads();

        half8 nav{}, nbv0{}, nbv1{}, nbv2{}, nbv3{};
        if (kt < 7) {
            const int k0 = (kt + 1) * 32;
            if (n0 + srow < N) nav = *reinterpret_cast<const half8*>(A + aoff + k0);
            nbv0 = *reinterpret_cast<const half8*>(WT + 0 * 65536 + boff + k0);
            nbv1 = *reinterpret_cast<const half8*>(WT + 1 * 65536 + boff + k0);
            nbv2 = *reinterpret_cast<const half8*>(WT + 2 * 65536 + boff + k0);
            nbv3 = *reinterpret_cast<const half8*>(WT + 3 * 65536 + boff + k0);
        }

        half8 af = *reinterpret_cast<const half8*>(&as[16 * w + (l & 15)][8 * (l >> 4)]);
        #pragma unroll
        for (int m = 0; m < 4; ++m) {
            #pragma unroll
            for (int b = 0; b < 4; ++b) {
                half8 bf = *reinterpret_cast<const half8*>(&bs[m][16 * b + (l & 15)][8 * (l >> 4)]);
                acc[m][b] = __builtin_amdgcn_mfma_f32_16x16x32_f16(af, bf, acc[m][b], 0, 0, 0);
            }
        }
        av = nav; bv0 = nbv0; bv1 = nbv1; bv2 = nbv2; bv3 = nbv3;
    }

    #pragma unroll
    for (int r = 0; r < 4; ++r) {
        const int grow = n0 + 16 * w + ((l >> 4) << 2) + r;
        if (grow >= N) continue;
        float a0 = pe[(size_t)grow * AFZ + (l & 15)];
        float a1 = pe[(size_t)grow * AFZ + 16 + (l & 15)];
        float s0, c0f, s1, c1f;
        __sincosf(a0, &s0, &c0f);
        __sincosf(a1, &s1, &c1f);
        #pragma unroll
        for (int m = 0; m < 2; ++m) {
            _Float16* o = m ? KH : QH;
            #pragma unroll
            for (int pb = 0; pb < 4; pb += 2) {
                float v0 = acc[m][pb][r], v1 = acc[m][pb + 1][r];
                o[(size_t)grow * HF + c0 + 16 * pb       + (l & 15)] = (_Float16)(v0 * c0f - v1 * s0);
                o[(size_t)grow * HF + c0 + 16 * (pb + 1) + (l & 15)] = (_Float16)(v1 * c1f + v0 * s1);
            }
        }
        #pragma unroll
        for (int b = 0; b < 4; ++b)
            VH[(size_t)grow * HF + c0 + 16 * b + (l & 15)] = (_Float16)acc[2][b][r];
        #pragma unroll
        for (int b = 0; b < 4; ++b) {
            const int c = c0 + 16 * b + (l & 15);
            float v = acc[3][b][r] + bg[c];
            GH[(size_t)grow * HF + c] = (_Float16)(1.f / (1.f + __expf(-v)));
        }
    }
}

// ---------------------------------------------------------------------------
// FUSED attention: one wave per node. Computes bias2 from x2 (node's own 16
// rows, MFMA trick) AND the gather/softmax/PV — x2 HBM streaming overlaps
// K/V gather latency across waves. No LDS, no __syncthreads, no B2 buffer.
// bias2 register mapping: bval[j] at lane (p=l>>4, c=l&15) = bias2[e=4p+j][h=c]
// ---------------------------------------------------------------------------
__launch_bounds__(256)
__global__ void attn_fused(const _Float16* __restrict__ Qh, const _Float16* __restrict__ Kh,
                           const _Float16* __restrict__ Vh, const _Float16* __restrict__ Gh,
                           const int* __restrict__ eidx, const float* __restrict__ x2,
                           const _Float16* __restrict__ c1T, const float* __restrict__ c23,
                           _Float16* __restrict__ AOh, int N)
{
    const int tid = threadIdx.x;
    const int l   = tid & 63;
    const int w   = tid >> 6;
    const int n   = blockIdx.x * 4 + w;
    if (n >= N) return;
    const int h = l >> 3;
    const int c = l & 15;
    const int p = l >> 4;

    // edge indices: lane c holds edge c (upper lane groups replicate)
    const int ei_reg = eidx[(size_t)n * KZ + c];

    // ---- bias2 inputs: x2 row (n*KZ + c), k-chunk p*8 ----
    const float* xr = x2 + ((size_t)n * KZ + c) * IFZ + p * 8;
    f32x4 xv[16];
    #pragma unroll
    for (int kt = 0; kt < 8; ++kt) {
        xv[2 * kt]     = __builtin_nontemporal_load(reinterpret_cast<const f32x4*>(xr + kt * 32));
        xv[2 * kt + 1] = __builtin_nontemporal_load(reinterpret_cast<const f32x4*>(xr + kt * 32 + 4));
    }
    half8 bf[8];
    #pragma unroll
    for (int kt = 0; kt < 8; ++kt)
        bf[kt] = *reinterpret_cast<const half8*>(c1T + (size_t)c * 256 + kt * 32 + p * 8);

    f32x4 acc1 = {0.f, 0.f, 0.f, 0.f};
    f32x4 acc2 = {0.f, 0.f, 0.f, 0.f};
    #pragma unroll
    for (int kt = 0; kt < 8; ++kt) {
        f32x4 xa = xv[2 * kt], xb = xv[2 * kt + 1];
        half8 ax, ax2;
        ax[0] = (_Float16)xa[0]; ax[1] = (_Float16)xa[1];
        ax[2] = (_Float16)xa[2]; ax[3] = (_Float16)xa[3];
        ax[4] = (_Float16)xb[0]; ax[5] = (_Float16)xb[1];
        ax[6] = (_Float16)xb[2]; ax[7] = (_Float16)xb[3];
        ax2[0] = (_Float16)(xa[0] * xa[0]); ax2[1] = (_Float16)(xa[1] * xa[1]);
        ax2[2] = (_Float16)(xa[2] * xa[2]); ax2[3] = (_Float16)(xa[3] * xa[3]);
        ax2[4] = (_Float16)(xb[0] * xb[0]); ax2[5] = (_Float16)(xb[1] * xb[1]);
        ax2[6] = (_Float16)(xb[2] * xb[2]); ax2[7] = (_Float16)(xb[3] * xb[3]);
        acc1 = __builtin_amdgcn_mfma_f32_16x16x32_f16(ax,  bf[kt], acc1, 0, 0, 0);
        acc2 = __builtin_amdgcn_mfma_f32_16x16x32_f16(ax2, bf[kt], acc2, 0, 0, 0);
    }

    // finalize bias2: bval[j] = bias2[e=4p+j][h=c]  (valid where c<8)
    const float c2v = (c < 8) ? c23[c]     : 0.f;
    const float c3v = (c < 8) ? c23[8 + c] : 0.f;
    const int srcl = (l & 48) | 8;   // col-8 lane (S1/S2) of this row-quad
    float bval[4];
    #pragma unroll
    for (int j = 0; j < 4; ++j) {
        float s1 = __shfl(acc1[j], srcl);
        float s2 = __shfl(acc2[j], srcl);
        float m    = s1 * (1.f / 256.f);
        float var  = s2 * (1.f / 256.f) - m * m;
        float rstd = rsqrtf(var + 1e-5f);
        bval[j] = rstd * (acc1[j] - m * c2v) + c3v;
    }

    // ---- attention ----
    half4 qh4 = *reinterpret_cast<const half4*>(Qh + (size_t)n * HF + 4 * l);
    const float q0 = (float)qh4[0], q1 = (float)qh4[1],
                q2 = (float)qh4[2], q3 = (float)qh4[3];

    float sc[16];
    #pragma unroll
    for (int e = 0; e < 16; ++e) {
        const int row = __shfl(ei_reg, e);
        half4 kh4 = *reinterpret_cast<const half4*>(Kh + (size_t)row * HF + 4 * l);
        float s = q0 * (float)kh4[0] + q1 * (float)kh4[1]
                + q2 * (float)kh4[2] + q3 * (float)kh4[3];
        s += __shfl_xor(s, 1); s += __shfl_xor(s, 2); s += __shfl_xor(s, 4);
        sc[e] = s * 0.17677669529663687f
              + __shfl(bval[e & 3], ((e >> 2) << 4) | h);
    }

    float m = sc[0];
    #pragma unroll
    for (int e = 1; e < 16; ++e) m = fmaxf(m, sc[e]);
    float sum = 0.f;
    #pragma unroll
    for (int e = 0; e < 16; ++e) { sc[e] = __expf(sc[e] - m); sum += sc[e]; }
    const float inv = 1.f / sum;

    float o0 = 0.f, o1 = 0.f, o2 = 0.f, o3 = 0.f;
    #pragma unroll
    for (int e = 0; e < 16; ++e) {
        const int row = __shfl(ei_reg, e);
        half4 vh4 = *reinterpret_cast<const half4*>(Vh + (size_t)row * HF + 4 * l);
        const float we = sc[e] * inv;
        o0 = fmaf(we, (float)vh4[0], o0);
        o1 = fmaf(we, (float)vh4[1], o1);
        o2 = fmaf(we, (float)vh4[2], o2);
        o3 = fmaf(we, (float)vh4[3], o3);
    }

    half4 gh4 = *reinterpret_cast<const half4*>(Gh + (size_t)n * HF + 4 * l);
    half4 oh;
    oh[0] = (_Float16)(o0 * (float)gh4[0]);
    oh[1] = (_Float16)(o1 * (float)gh4[1]);
    oh[2] = (_Float16)(o2 * (float)gh4[2]);
    oh[3] = (_Float16)(o3 * (float)gh4[3]);
    *reinterpret_cast<half4*>(AOh + (size_t)n * HF + 4 * l) = oh;
}

// ---------------------------------------------------------------------------
// back-GEMM: LDS-staged 64x64 tiles + reg prefetch; Y = AO@Wback + bbk (f32)
// ---------------------------------------------------------------------------
__launch_bounds__(256)
__global__ void gemm_back(const _Float16* __restrict__ A, const _Float16* __restrict__ BT,
                          const float* __restrict__ bias, float* __restrict__ Y, int N)
{
    __shared__ _Float16 as[64][40];
    __shared__ _Float16 bs[64][40];

    const int tid = threadIdx.x;
    const int l   = tid & 63;
    const int w   = tid >> 6;
    const int n0  = blockIdx.x * 64;
    const int c0  = blockIdx.y * 64;

    f32x4 acc[4];
    #pragma unroll
    for (int b = 0; b < 4; ++b) { acc[b][0]=0.f; acc[b][1]=0.f; acc[b][2]=0.f; acc[b][3]=0.f; }

    const int srow = tid >> 2;
    const int sch  = (tid & 3) * 8;
    const size_t aoff = (size_t)(n0 + srow) * IFZ + sch;
    const size_t boff = (size_t)(c0 + srow) * IFZ + sch;

    half8 av{}, bv;
    if (n0 + srow < N) av = *reinterpret_cast<const half8*>(A + aoff);
    bv = *reinterpret_cast<const half8*>(BT + boff);

    for (int kt = 0; kt < 8; ++kt) {
        __syncthreads();
        *reinterpret_cast<half8*>(&as[srow][sch]) = av;
        *reinterpret_cast<half8*>(&bs[srow][sch]) = bv;
        __syncthreads();

        half8 nav{}, nbv{};
        if (kt < 7) {
            const int k0 = (kt + 1) * 32;
            if (n0 + srow < N) nav = *reinterpret_cast<const half8*>(A + aoff + k0);
            nbv = *reinterpret_cast<const half8*>(BT + boff + k0);
        }

        half8 af = *reinterpret_cast<const half8*>(&as[16 * w + (l & 15)][8 * (l >> 4)]);
        #pragma unroll
        for (int b = 0; b < 4; ++b) {
            half8 bf = *reinterpret_cast<const half8*>(&bs[16 * b + (l & 15)][8 * (l >> 4)]);
            acc[b] = __builtin_amdgcn_mfma_f32_16x16x32_f16(af, bf, acc[b], 0, 0, 0);
        }
        av = nav; bv = nbv;
    }

    #pragma unroll
    for (int r = 0; r < 4; ++r) {
        const int grow = n0 + 16 * w + ((l >> 4) << 2) + r;
        if (grow >= N) continue;
        #pragma unroll
        for (int b = 0; b < 4; ++b) {
            const int c = c0 + 16 * b + (l & 15);
            Y[(size_t)grow * HF + c] = acc[b][r] + bias[c];
        }
    }
}

// ---------------------------------------------------------------------------
// final: LN( RAW + sqrt(2)*x1 ) -> out     (one wave per row)
// ---------------------------------------------------------------------------
__launch_bounds__(256)
__global__ void final_ln(const float* __restrict__ RAWb,
                         const float* __restrict__ x1b,
                         const float* __restrict__ g1,
                         const float* __restrict__ b1,
                         float* __restrict__ outb,
                         int N)
{
    int n    = blockIdx.x * 4 + (threadIdx.x >> 6);
    int lane = threadIdx.x & 63;
    if (n >= N) return;
    const size_t off = (size_t)n * IFZ + lane * 4;
    float4 ur = *reinterpret_cast<const float4*>(RAWb + off);
    float4 ux = *reinterpret_cast<const float4*>(x1b + off);
    float x[4];
    x[0] = ur.x + 1.4142135623730951f * ux.x;
    x[1] = ur.y + 1.4142135623730951f * ux.y;
    x[2] = ur.z + 1.4142135623730951f * ux.z;
    x[3] = ur.w + 1.4142135623730951f * ux.w;
    float s = x[0] + x[1] + x[2] + x[3];
    float q = x[0]*x[0] + x[1]*x[1] + x[2]*x[2] + x[3]*x[3];
    #pragma unroll
    for (int o = 32; o > 0; o >>= 1) { s += __shfl_xor(s, o); q += __shfl_xor(q, o); }
    float m    = s * (1.f / 256.f);
    float var  = q * (1.f / 256.f) - m * m;
    float rstd = rsqrtf(var + 1e-5f);
    float4 uo;
    {
        int f = lane * 4;
        uo.x = (x[0] - m) * rstd * g1[f + 0] + b1[f + 0];
        uo.y = (x[1] - m) * rstd * g1[f + 1] + b1[f + 1];
        uo.z = (x[2] - m) * rstd * g1[f + 2] + b1[f + 2];
        uo.w = (x[3] - m) * rstd * g1[f + 3] + b1[f + 3];
    }
    *reinterpret_cast<float4*>(outb + off) = uo;
}

// ---------------------------------------------------------------------------
extern "C" void kernel_launch(void* const* d_in, const int* in_sizes, int n_in,
                              void* d_out, int out_size, void* d_ws, size_t ws_size,
                              hipStream_t stream)
{
    const float* x1   = (const float*)d_in[0];
    const float* x2   = (const float*)d_in[1];
    const float* pe   = (const float*)d_in[2];
    const int*   ei   = (const int*)d_in[3];
    const float* wq   = (const float*)d_in[4];
    const float* wk   = (const float*)d_in[5];
    const float* wv   = (const float*)d_in[6];
    const float* wb   = (const float*)d_in[7];
    const float* blng = (const float*)d_in[8];
    const float* blnb = (const float*)d_in[9];
    const float* wg   = (const float*)d_in[10];
    const float* bg   = (const float*)d_in[11];
    const float* wbk  = (const float*)d_in[12];
    const float* bbk  = (const float*)d_in[13];
    const float* g1   = (const float*)d_in[14];
    const float* b1   = (const float*)d_in[15];

    const int N = in_sizes[0] / IFZ;

    const size_t S2 = (((size_t)N * HF * 2) + 4095) & ~(size_t)4095;   // f16 buffer size
    char* base = (char*)d_ws;
    _Float16* X1H = (_Float16*)(base);
    _Float16* QH  = (_Float16*)(base + 1 * S2);
    _Float16* KH  = (_Float16*)(base + 2 * S2);
    _Float16* VH  = (_Float16*)(base + 3 * S2);
    _Float16* GH  = (_Float16*)(base + 4 * S2);
    _Float16* WT  = (_Float16*)(base + 5 * S2);                 // 5 x 65536 f16 (640KB)
    _Float16* C1T = (_Float16*)(base + 5 * S2 + (1u << 20));    // 16x256 f16
    float*    C23 = (float*)   (base + 5 * S2 + (1u << 20) + 8192);
    _Float16* AOH = QH;                  // reuse: wave n reads Q[n] then writes AO[n]
    float*    RAW = (float*)(base + 2 * S2);   // reuse KH+VH region (f32, 2*S2 bytes)

    conv_f16<<<dim3((N * IFZ / 4 + 255) / 256), 256, 0, stream>>>(x1, X1H, N * IFZ / 4);
    prep_all<<<dim3(256, 6), 256, 0, stream>>>(wq, wk, wv, wg, wbk, WT,
                                               blng, blnb, wb, C1T, C23);

    const int nt = (N + 63) / 64;
    gemm_qkvg<<<dim3(nt, 4), 256, 0, stream>>>(X1H, WT, pe, bg, QH, KH, VH, GH, N);

    attn_fused<<<dim3((N + 3) / 4), 256, 0, stream>>>(QH, KH, VH, GH, ei, x2,
                                                      C1T, C23, AOH, N);

    gemm_back<<<dim3(nt, 4), 256, 0, stream>>>(AOH, WT + 4 * 65536, bbk, RAW, N);

    final_ln<<<dim3((N + 3) / 4), 256, 0, stream>>>(RAW, x1, g1, b1, (float*)d_out, N);
}